// Round 3
// baseline (245.964 us; speedup 1.0000x reference)
//
#include <hip/hip_runtime.h>
#include <cstdint>

typedef unsigned short u16;
typedef unsigned int u32;

typedef short bf16x8 __attribute__((ext_vector_type(8)));
typedef float f32x4 __attribute__((ext_vector_type(4)));

#define LN2 0.69314718055994530942f
#define LOG2E 1.44269504088896340736f
#define INFF __builtin_inff()

__device__ __forceinline__ u16 f2bf(float f) {
  u32 u = __float_as_uint(f);
  u = (u + 0x7fffu + ((u >> 16) & 1u)) >> 16;
  return (u16)u;
}
__device__ __forceinline__ u32 pack2bf(float a, float b) {
  u32 ta = __float_as_uint(a) + 0x8000u;
  u32 tb = __float_as_uint(b) + 0x8000u;
  return __builtin_amdgcn_perm(tb, ta, 0x07060302u);
}

#if __has_builtin(__builtin_amdgcn_global_load_lds)
#define HAVE_GLDS 1
__device__ __forceinline__ void glds16(const u16* g, u16* l) {
  __builtin_amdgcn_global_load_lds((const __attribute__((address_space(1))) void*)g,
                                   (__attribute__((address_space(3))) void*)l, 16, 0, 0);
}
#else
#define HAVE_GLDS 0
#endif

// XOR-swizzled LDS addressing for [64][64] u16 tiles (128B rows).
// byte ^= ((row&7)<<4). Measured: SQ_LDS_BANK_CONFLICT 5.9M -> 1.08M.
__device__ __forceinline__ u16* swzp(u16* base, int row, int bc) {
  return (u16*)((char*)base + row * 128 + (bc ^ ((row & 7) << 4)));
}

// ---------------- prep kernels ----------------

__global__ void k_convert_x(const float* __restrict__ in, u16* __restrict__ out, int n4) {
  int i = blockIdx.x * blockDim.x + threadIdx.x;
  if (i < n4) {
    float4 v = ((const float4*)in)[i];
    ushort4 o;
    o.x = f2bf(v.x); o.y = f2bf(v.y); o.z = f2bf(v.z); o.w = f2bf(v.w);
    ((ushort4*)out)[i] = o;
  }
}

__global__ void k_transpose_bf(const float* __restrict__ in, u16* __restrict__ out, int R, int C) {
  __shared__ float t[32][33];
  int c0 = blockIdx.x * 32, r0 = blockIdx.y * 32;
  int tx = threadIdx.x, ty = threadIdx.y;
#pragma unroll
  for (int k = 0; k < 4; k++) t[ty + 8 * k][tx] = in[(size_t)(r0 + ty + 8 * k) * C + c0 + tx];
  __syncthreads();
#pragma unroll
  for (int k = 0; k < 4; k++) out[(size_t)(c0 + ty + 8 * k) * R + r0 + tx] = f2bf(t[tx][ty + 8 * k]);
}

__global__ void k_tables(const float* __restrict__ cP, const float* __restrict__ lP,
                         float* __restrict__ ig2, float* __restrict__ rl) {
  int t = blockIdx.x * blockDim.x + threadIdx.x;
  float c = fabsf(cP[0]);
  if (t < 2048) {
    float lm = lP[0];
    float thr = fabsf(lm * 512.0f);
    float pn = fmaxf((float)t, thr);
    float den = logf(c * pn + 1.0f) + 1e-6f;
    ig2[t] = LN2 / den;
  }
  if (t < 2112) {
    int d = t - 63;
    if (d < 0) d = 0;
    rl[t] = log2f(c * (float)d + 1.0f);
  }
}

__global__ void k_segments(const float* __restrict__ w1, const float* __restrict__ b1,
                           const float* __restrict__ w2, const float* __restrict__ b2,
                           float* __restrict__ segX, float* __restrict__ segA,
                           float* __restrict__ segB, int* __restrict__ segU) {
  __shared__ float xs[32];
  __shared__ float srt[32];
  __shared__ float uniq[32];
  __shared__ int uCnt;
  int t = threadIdx.x;
  if (t < 32) {
    float w = w1[t], b = b1[t];
    xs[t] = (w != 0.0f) ? (-b / w) : INFF;
  }
  __syncthreads();
  if (t < 32) {
    float x = xs[t];
    int r = 0;
    for (int v = 0; v < 32; v++) {
      float xv = xs[v];
      if (xv < x || (xv == x && v < t)) r++;
    }
    srt[r] = x;
  }
  __syncthreads();
  if (t == 0) {
    int u = 0;
    for (int i = 0; i < 32; i++) {
      float v = srt[i];
      if (v < 3.0e38f && (u == 0 || v != uniq[u - 1])) uniq[u++] = v;
    }
    uCnt = u;
    segU[0] = u;
  }
  __syncthreads();
  int u = uCnt;
  if (t < u) segX[t] = uniq[t];
  for (int idx = t; idx < (u + 1) * 16; idx += blockDim.x) {
    int j = idx >> 4, h = idx & 15;
    float p;
    if (u == 0) p = 0.0f;
    else if (j == 0) p = uniq[0] - 1.0f;
    else if (j == u) p = uniq[u - 1] + 1.0f;
    else p = 0.5f * (uniq[j - 1] + uniq[j]);
    float A = b2[h], B = 0.0f;
    for (int w = 0; w < 32; w++) {
      float w1w = w1[w], b1w = b1[w], w2wh = w2[w * 16 + h];
      if (w1w != 0.0f) {
        if (fmaf(w1w, p, b1w) > 0.0f) { B += w1w * w2wh; A += b1w * w2wh; }
      } else if (b1w > 0.0f) {
        A += b1w * w2wh;
      }
    }
    segA[j * 16 + h] = A;
    segB[j * 16 + h] = B;
  }
}

// ---------------- GEMM:  C(MxN) = A(MxK) @ BT(NxK)^T ----------------
template <int MODE, int BN>
__launch_bounds__(256, 3)
__global__ void k_gemm(const u16* __restrict__ A, const u16* __restrict__ BT,
                       const float* __restrict__ bias, float* __restrict__ outF,
                       u16* __restrict__ outQ, u16* __restrict__ outK, u16* __restrict__ outV,
                       int M, int N, int K) {
  constexpr int NT = BN / 32;
  constexpr int NCH = BN / 32;
  __shared__ u16 As[128 * 64];
  __shared__ u16 Bs[BN * 64];
  const int tid = threadIdx.x;
  const int lane = tid & 63, wave = tid >> 6;
  const int li = lane & 15, quad = lane >> 4;
  const int wrow = (wave >> 1) * 64, wcol = (wave & 1) * (BN / 2);
  const int rb = blockIdx.y * 128, cb = blockIdx.x * BN;

  f32x4 acc[4][NT];
#pragma unroll
  for (int i = 0; i < 4; i++)
#pragma unroll
    for (int j = 0; j < NT; j++) acc[i][j] = (f32x4){0.f, 0.f, 0.f, 0.f};

#if HAVE_GLDS
  const u16* gA = A + (size_t)(rb + (tid >> 3)) * K + (tid & 7) * 8;
  const u16* gB = BT + (size_t)(cb + (tid >> 3)) * K + (tid & 7) * 8;
  u16* lA = As + wave * 512;
  u16* lB = Bs + wave * 512;

  for (int k0 = 0; k0 < K; k0 += 64) {
    __syncthreads();
#pragma unroll
    for (int ch = 0; ch < 4; ch++) glds16(gA + (size_t)ch * 32 * K + k0, lA + ch * 2048);
#pragma unroll
    for (int ch = 0; ch < NCH; ch++) glds16(gB + (size_t)ch * 32 * K + k0, lB + ch * 2048);
    __syncthreads();
#pragma unroll
    for (int c = 0; c < 2; c++) {
      bf16x8 af[4], bfr[NT];
#pragma unroll
      for (int mt = 0; mt < 4; mt++)
        af[mt] = *(const bf16x8*)(&As[(wrow + mt * 16 + li) * 64 + c * 32 + quad * 8]);
#pragma unroll
      for (int nt = 0; nt < NT; nt++)
        bfr[nt] = *(const bf16x8*)(&Bs[(wcol + nt * 16 + li) * 64 + c * 32 + quad * 8]);
#pragma unroll
      for (int mt = 0; mt < 4; mt++)
#pragma unroll
        for (int nt = 0; nt < NT; nt++)
          acc[mt][nt] = __builtin_amdgcn_mfma_f32_16x16x32_bf16(af[mt], bfr[nt], acc[mt][nt], 0, 0, 0);
    }
  }
#else
  for (int k0 = 0; k0 < K; k0 += 64) {
    __syncthreads();
    for (int idx = tid * 8; idx < 128 * 64; idx += 256 * 8) {
      int rr = idx >> 6, cc = idx & 63;
      *(uint4*)(&As[idx]) = *(const uint4*)(A + (size_t)(rb + rr) * K + k0 + cc);
    }
    for (int idx = tid * 8; idx < BN * 64; idx += 256 * 8) {
      int rr = idx >> 6, cc = idx & 63;
      *(uint4*)(&Bs[idx]) = *(const uint4*)(BT + (size_t)(cb + rr) * K + k0 + cc);
    }
    __syncthreads();
#pragma unroll
    for (int c = 0; c < 2; c++) {
      bf16x8 af[4], bfr[NT];
#pragma unroll
      for (int mt = 0; mt < 4; mt++)
        af[mt] = *(const bf16x8*)(&As[(wrow + mt * 16 + li) * 64 + c * 32 + quad * 8]);
#pragma unroll
      for (int nt = 0; nt < NT; nt++)
        bfr[nt] = *(const bf16x8*)(&Bs[(wcol + nt * 16 + li) * 64 + c * 32 + quad * 8]);
#pragma unroll
      for (int mt = 0; mt < 4; mt++)
#pragma unroll
        for (int nt = 0; nt < NT; nt++)
          acc[mt][nt] = __builtin_amdgcn_mfma_f32_16x16x32_bf16(af[mt], bfr[nt], acc[mt][nt], 0, 0, 0);
    }
  }
#endif

#pragma unroll
  for (int mt = 0; mt < 4; mt++)
#pragma unroll
    for (int nt = 0; nt < NT; nt++)
#pragma unroll
      for (int r = 0; r < 4; r++) {
        int row = rb + wrow + mt * 16 + quad * 4 + r;
        int col = cb + wcol + nt * 16 + li;
        float v = acc[mt][nt][r] + bias[col];
        if (MODE == 0) {
          int b = row >> 11, tt = row & 2047;
          int sel = col >> 10, w = col & 1023, h = w >> 6, dd = w & 63;
          u16* dst = (sel == 0) ? outQ : ((sel == 1) ? outK : outV);
          dst[(size_t)((b * 16 + h) * 2048 + tt) * 64 + dd] = f2bf(v);
        } else {
          outF[(size_t)row * N + col] = v;
        }
      }
}

// ---------------- flash attention, S^T formulation, split-K ----------------
// Round-2 finding: 1024 one-tile blocks give time-avg residency of only
// ~2 blocks/CU (short blocks drain, nothing refills) -> Occupancy 19%,
// VALUBusy 42%, latency-bound. Fix: split-K. qt>=16 tiles split into two
// k-halves (8..16 iterations each, partials combined by k_combine); qt<16
// run whole (<=16 iter). Grid 48x16x2 = 1536 blocks = 6/CU queue, 4 resident
// (LDS 33KB). Dispatch order: long blocks first, 1..4-iter blocks last.
// __launch_bounds__(256,3): (256,4) forces VGPR<=64 and spills (round 1:
// WRITE_SIZE 8->39MB). At VGPR~84, LDS is the residency limit (4 blocks/CU).
__launch_bounds__(256, 3)
__global__ void k_attn(const u16* __restrict__ Q, const u16* __restrict__ K,
                       const u16* __restrict__ V, u16* __restrict__ Y,
                       float* __restrict__ PO, float* __restrict__ ML,
                       const float* __restrict__ ig2, const float* __restrict__ RL,
                       const float* __restrict__ segX, const float* __restrict__ segA,
                       const float* __restrict__ segB, const int* __restrict__ segU) {
  __shared__ u16 Ks[64 * 64];
  __shared__ u16 Vts[64 * 64];  // transposed: Vts[d][kk]
  __shared__ u16 Ps[64 * 64];   // Ps[q][s] (wave-private rows)
  __shared__ float rls[2112];
  __shared__ float sXl[32];
  __shared__ float sAl[33];
  __shared__ float sBl[33];

  const int xi = blockIdx.x, h = blockIdx.y, b = blockIdx.z;
  int qt, k0, k1, half, split;
  if (xi < 32) {  // split tiles, qt 31..16, two halves each
    qt = 31 - (xi >> 1);
    half = xi & 1;
    split = 1;
    const int h0 = (qt + 2) >> 1;  // ceil((qt+1)/2), in [9,16]
    k0 = half ? h0 : 0;
    k1 = half ? (qt + 1) : h0;
  } else {  // whole tiles, qt 15..0
    qt = 47 - xi;
    half = 0;
    split = 0;
    k0 = 0;
    k1 = qt + 1;
  }

  const int tid = threadIdx.x, lane = tid & 63, wave = tid >> 6;
  const int li = lane & 15, quad = lane >> 4;
  const int bh = b * 16 + h;
  const u16* Qg = Q + (size_t)bh * 2048 * 64;
  const u16* Kg = K + (size_t)bh * 2048 * 64;
  const u16* Vg = V + (size_t)bh * 2048 * 64;

  for (int i = tid; i < 2112; i += 256) rls[i] = RL[i];

  const int u = segU[0];
  float x0 = INFF, A0, B0, A1, B1;
  A0 = segA[h]; B0 = segB[h]; A1 = A0; B1 = B0;
  if (u == 1) { x0 = segX[0]; A1 = segA[16 + h]; B1 = segB[16 + h]; }
  if (u > 1) {
    if (tid < u) sXl[tid] = segX[tid];
    if (tid < u + 1) { sAl[tid] = segA[tid * 16 + h]; sBl[tid] = segB[tid * 16 + h]; }
  }
  const float A0e = A0 * LOG2E, A1e = A1 * LOG2E;
  const float SCL = 0.125f * LOG2E;

  const int qw = qt * 64 + wave * 16;
  const int t = qw + li;  // this lane's q-row
  bf16x8 qf[2];
#pragma unroll
  for (int c = 0; c < 2; c++)
    qf[c] = *(const bf16x8*)(Qg + (size_t)t * 64 + c * 32 + quad * 8);

  const float gI = ig2[t];
  const float x0r = x0 / gI;
  const float B0g = B0 * gI * LOG2E, B1g = B1 * gI * LOG2E;
  float mrow = -INFF, lrow = 0.0f;
  f32x4 oacc[4];
#pragma unroll
  for (int nt = 0; nt < 4; nt++) oacc[nt] = (f32x4){0.f, 0.f, 0.f, 0.f};

  // prefetch kt = k0 into registers
  uint4 kv0, kv1, w0, w1;
  {
    const u16* ksrc = Kg + (size_t)(k0 * 64 + (tid >> 2)) * 64 + (tid & 3) * 16;
    kv0 = *(const uint4*)(ksrc);
    kv1 = *(const uint4*)(ksrc + 8);
    const u16* vsrc = Vg + (size_t)(k0 * 64 + 2 * (tid & 31)) * 64 + (tid >> 5) * 8;
    w0 = *(const uint4*)(vsrc);
    w1 = *(const uint4*)(vsrc + 64);
  }

  const int krow = tid >> 2, kcol = (tid & 3) * 32;  // K staging coords (bytes)
  const int kkp = tid & 31, d0v = (tid >> 5) * 8;    // V staging coords

  for (int kt = k0; kt < k1; kt++) {
    const int kb = kt * 64;
    __syncthreads();  // previous iteration's LDS readers done
    *(uint4*)swzp(Ks, krow, kcol) = kv0;
    *(uint4*)swzp(Ks, krow, kcol + 16) = kv1;
    {
      const u16* pw0 = (const u16*)&w0;
      const u16* pw1 = (const u16*)&w1;
#pragma unroll
      for (int j = 0; j < 8; j++)
        *(u32*)swzp(Vts, d0v + j, 4 * kkp) = (u32)pw0[j] | ((u32)pw1[j] << 16);
    }
    __syncthreads();
    if (kt + 1 < k1) {  // prefetch next tile; in flight through the compute below
      const u16* ksrc = Kg + (size_t)(kb + 64 + (tid >> 2)) * 64 + (tid & 3) * 16;
      kv0 = *(const uint4*)(ksrc);
      kv1 = *(const uint4*)(ksrc + 8);
      const u16* vsrc = Vg + (size_t)(kb + 64 + 2 * (tid & 31)) * 64 + (tid >> 5) * 8;
      w0 = *(const uint4*)(vsrc);
      w1 = *(const uint4*)(vsrc + 64);
    }

    // S^T = K Q^T : sacc[nt] row s = nt*16+quad*4+r, col q = li
    f32x4 sacc[4];
#pragma unroll
    for (int nt = 0; nt < 4; nt++) sacc[nt] = (f32x4){0.f, 0.f, 0.f, 0.f};
#pragma unroll
    for (int c = 0; c < 2; c++)
#pragma unroll
      for (int nt = 0; nt < 4; nt++) {
        bf16x8 kf = *(const bf16x8*)swzp(Ks, nt * 16 + li, c * 64 + quad * 16);
        sacc[nt] = __builtin_amdgcn_mfma_f32_16x16x32_bf16(kf, qf[c], sacc[nt], 0, 0, 0);
      }

    // bias via rl table (LDS)
    const int Cbase = t - kb - quad * 4 + 63;  // in [51, 2110]
    const float* rp = &rls[Cbase - 51];
    if (u <= 1) {
      const int lim = Cbase - 63;
#pragma unroll
      for (int nt = 0; nt < 4; nt++)
#pragma unroll
        for (int r = 0; r < 4; r++) {
          float rlv = rp[51 - nt * 16 - r];
          bool hi = rlv > x0r;
          float z = fmaf(rlv, hi ? B1g : B0g, hi ? A1e : A0e);
          z = fmaf(sacc[nt][r], SCL, z);
          if (kt == qt) z = (nt * 16 + r > lim) ? -INFF : z;
          sacc[nt][r] = z;
        }
    } else {
      const int lim = Cbase - 63;
#pragma unroll
      for (int nt = 0; nt < 4; nt++)
#pragma unroll
        for (int r = 0; r < 4; r++) {
          float nd = rp[51 - nt * 16 - r] * gI;
          int j = 0;
          for (int i = 0; i < u; i++) j += (nd > sXl[i]) ? 1 : 0;
          float z = (fmaf(nd, sBl[j], sAl[j]) + sacc[nt][r] * 0.125f) * LOG2E;
          if (kt == qt) z = (nt * 16 + r > lim) ? -INFF : z;
          sacc[nt][r] = z;
        }
    }

    // per-lane online softmax (row q = li) — tree-shaped max and sum
    f32x4 mm = sacc[0];
#pragma unroll
    for (int nt = 1; nt < 4; nt++)
#pragma unroll
      for (int r = 0; r < 4; r++) mm[r] = fmaxf(mm[r], sacc[nt][r]);
    float vm = fmaxf(fmaxf(mm[0], mm[1]), fmaxf(mm[2], mm[3]));
    vm = fmaxf(vm, __shfl_xor(vm, 16, 64));
    vm = fmaxf(vm, __shfl_xor(vm, 32, 64));
    float mnew = fmaxf(mrow, vm);
    bool grew = mnew > mrow;
    float alpha = __builtin_amdgcn_exp2f(mrow - mnew);
    mrow = mnew;
#pragma unroll
    for (int nt = 0; nt < 4; nt++)
#pragma unroll
      for (int r = 0; r < 4; r++)
        sacc[nt][r] = __builtin_amdgcn_exp2f(sacc[nt][r] - mnew);
    f32x4 sv = (sacc[0] + sacc[1]) + (sacc[2] + sacc[3]);
    float s = (sv[0] + sv[1]) + (sv[2] + sv[3]);
    s += __shfl_xor(s, 16, 64);
    s += __shfl_xor(s, 32, 64);
    lrow = lrow * alpha + s;
    if (__any(grew)) {  // skip the 16-mul rescale when no lane's max moved
#pragma unroll
      for (int nt = 0; nt < 4; nt++)
#pragma unroll
        for (int r = 0; r < 4; r++) oacc[nt][r] *= alpha;
    }

    // P^T -> Ps[q][s]; wave-private rows, b64 writes
    const int prow = wave * 16 + li;
#pragma unroll
    for (int nt = 0; nt < 4; nt++) {
      uint2 pk;
      pk.x = pack2bf(sacc[nt][0], sacc[nt][1]);
      pk.y = pack2bf(sacc[nt][2], sacc[nt][3]);
      *(uint2*)swzp(Ps, prow, 32 * nt + 8 * quad) = pk;
    }

    // O^T += V^T P^T
#pragma unroll
    for (int c = 0; c < 2; c++) {
      bf16x8 pf = *(const bf16x8*)swzp(Ps, prow, c * 64 + quad * 16);
#pragma unroll
      for (int nt = 0; nt < 4; nt++) {
        bf16x8 vf = *(const bf16x8*)swzp(Vts, nt * 16 + li, c * 64 + quad * 16);
        oacc[nt] = __builtin_amdgcn_mfma_f32_16x16x32_bf16(vf, pf, oacc[nt], 0, 0, 0);
      }
    }
  }

  if (split) {
    // unnormalized partial: PO[p][q][d] (f32) + ML[p][q] = (m, l)
    const int p = bh * 32 + (qt - 16) * 2 + half;
    const int qr = wave * 16 + li;
    float* po = PO + (size_t)p * 4096 + (size_t)qr * 64 + quad * 4;
#pragma unroll
    for (int nt = 0; nt < 4; nt++) {
      float4 v4 = make_float4(oacc[nt][0], oacc[nt][1], oacc[nt][2], oacc[nt][3]);
      *(float4*)(po + nt * 16) = v4;
    }
    if (quad == 0) {
      ML[p * 128 + qr * 2] = mrow;
      ML[p * 128 + qr * 2 + 1] = lrow;
    }
  } else {
    // epilogue: O^T element (d = nt*16+quad*4+r, q = li) -> Y[b][t][h*64+d]
    float inv = 1.0f / lrow;
    u16* dst = Y + (size_t)(b * 2048 + t) * 1024 + h * 64 + quad * 4;
#pragma unroll
    for (int nt = 0; nt < 4; nt++) {
      uint2 pk;
      pk.x = pack2bf(oacc[nt][0] * inv, oacc[nt][1] * inv);
      pk.y = pack2bf(oacc[nt][2] * inv, oacc[nt][3] * inv);
      *(uint2*)(dst + nt * 16) = pk;
    }
  }
}

// ---------------- combine split-K partials (rows t >= 1024) ----------------
__global__ void k_combine(const float* __restrict__ PO, const float* __restrict__ ML,
                          u16* __restrict__ Y) {
  const int gid = blockIdx.x * 256 + threadIdx.x;  // 524288 total
  const int d4 = gid & 15;
  const int row = (gid >> 4) & 1023;  // t - 1024
  const int bh = gid >> 14;           // [0,32)
  const int qt16 = row >> 6, r = row & 63;
  const int p0 = bh * 32 + qt16 * 2;
  const float* o0 = PO + (size_t)p0 * 4096 + (size_t)r * 64 + d4 * 4;
  const float* o1 = o0 + 4096;
  const float m0 = ML[p0 * 128 + r * 2], l0 = ML[p0 * 128 + r * 2 + 1];
  const float m1 = ML[(p0 + 1) * 128 + r * 2], l1 = ML[(p0 + 1) * 128 + r * 2 + 1];
  const float m = fmaxf(m0, m1);
  const float e0 = __builtin_amdgcn_exp2f(m0 - m);
  const float e1 = __builtin_amdgcn_exp2f(m1 - m);
  const float inv = 1.0f / (l0 * e0 + l1 * e1);
  const float4 a = *(const float4*)o0;
  const float4 c = *(const float4*)o1;
  const int t = 1024 + row, b = bh >> 4, h = bh & 15;
  u16* dst = Y + (size_t)(b * 2048 + t) * 1024 + h * 64 + d4 * 4;
  uint2 pk;
  pk.x = pack2bf(fmaf(a.x, e0, c.x * e1) * inv, fmaf(a.y, e0, c.y * e1) * inv);
  pk.y = pack2bf(fmaf(a.z, e0, c.z * e1) * inv, fmaf(a.w, e0, c.w * e1) * inv);
  *(uint2*)dst = pk;
}

// ---------------- launcher ----------------
extern "C" void kernel_launch(void* const* d_in, const int* in_sizes, int n_in,
                              void* d_out, int out_size, void* d_ws, size_t ws_size,
                              hipStream_t stream) {
  (void)in_sizes; (void)n_in; (void)out_size; (void)ws_size;
  const float* x = (const float*)d_in[0];
  const float* Wqkv = (const float*)d_in[1];
  const float* bqkv = (const float*)d_in[2];
  const float* Wproj = (const float*)d_in[3];
  const float* bproj = (const float*)d_in[4];
  const float* w1 = (const float*)d_in[5];
  const float* b1 = (const float*)d_in[6];
  const float* w2 = (const float*)d_in[7];
  const float* b2 = (const float*)d_in[8];
  const float* cP = (const float*)d_in[9];
  const float* lP = (const float*)d_in[10];

  // Workspace layout (MB offsets):
  //  [0,16)  prep: Xbf[0,8) + WqkvT[8,14)        -- dead after GEMM1
  //          attn: PO split-K partials (16MB exactly, overlays prep region)
  //  [16,24) Qb   [24,32) Kb   [32,40) Vb   [40,48) Yb
  //  [48,~)  tables (IG/RL/SEG*, ~21KB)
  //  [49,51) WprojT (relocated: old [14,16) slot is now PO territory)
  //  [51,51.5) ML split-K (m,l) partials
  char* ws = (char*)d_ws;
  u16* Xbf = (u16*)(ws);
  u16* WqkvT = (u16*)(ws + (size_t)(8 << 20));
  u16* Qb = (u16*)(ws + (size_t)(16 << 20));
  u16* Kb = (u16*)(ws + (size_t)(24 << 20));
  u16* Vb = (u16*)(ws + (size_t)(32 << 20));
  u16* Yb = (u16*)(ws + (size_t)(40 << 20));
  float* IG = (float*)(ws + (size_t)(48 << 20));
  float* RL = IG + 2048;
  float* SEGX = RL + 2112;
  float* SEGA = SEGX + 32;
  float* SEGB = SEGA + 33 * 16;
  int* SEGU = (int*)(SEGB + 33 * 16);
  u16* WprojT = (u16*)(ws + (size_t)(49 << 20));
  float* PO = (float*)(ws);
  float* ML = (float*)(ws + (size_t)(51 << 20));

  k_convert_x<<<4096, 256, 0, stream>>>(x, Xbf, 1048576);
  k_transpose_bf<<<dim3(96, 32), dim3(32, 8), 0, stream>>>(Wqkv, WqkvT, 1024, 3072);
  k_transpose_bf<<<dim3(32, 32), dim3(32, 8), 0, stream>>>(Wproj, WprojT, 1024, 1024);
  k_tables<<<9, 256, 0, stream>>>(cP, lP, IG, RL);
  k_segments<<<1, 64, 0, stream>>>(w1, b1, w2, b2, SEGX, SEGA, SEGB, SEGU);

  k_gemm<0, 128><<<dim3(24, 32), 256, 0, stream>>>(Xbf, WqkvT, bqkv, nullptr, Qb, Kb, Vb,
                                                   4096, 3072, 1024);
  k_attn<<<dim3(48, 16, 2), 256, 0, stream>>>(Qb, Kb, Vb, Yb, PO, ML, IG, RL, SEGX, SEGA,
                                              SEGB, SEGU);
  k_combine<<<2048, 256, 0, stream>>>(PO, ML, Yb);
  k_gemm<1, 64><<<dim3(16, 32), 256, 0, stream>>>(Yb, WprojT, bproj, (float*)d_out, nullptr,
                                                  nullptr, nullptr, 4096, 1024, 1024);
}

// Round 4
// 239.914 us; speedup vs baseline: 1.0252x; 1.0252x over previous
//
#include <hip/hip_runtime.h>
#include <cstdint>

typedef unsigned short u16;
typedef unsigned int u32;

typedef short bf16x8 __attribute__((ext_vector_type(8)));
typedef float f32x4 __attribute__((ext_vector_type(4)));

#define LN2 0.69314718055994530942f
#define LOG2E 1.44269504088896340736f
#define INFF __builtin_inff()

__device__ __forceinline__ u16 f2bf(float f) {
  u32 u = __float_as_uint(f);
  u = (u + 0x7fffu + ((u >> 16) & 1u)) >> 16;
  return (u16)u;
}
__device__ __forceinline__ u32 pack2bf(float a, float b) {
  u32 ta = __float_as_uint(a) + 0x8000u;
  u32 tb = __float_as_uint(b) + 0x8000u;
  return __builtin_amdgcn_perm(tb, ta, 0x07060302u);
}
// RNE-packed pair (matches f2bf numerics; used for V so attn sees identical values)
__device__ __forceinline__ u32 pack2bf_rne(float a, float b) {
  return (u32)f2bf(a) | ((u32)f2bf(b) << 16);
}

#if __has_builtin(__builtin_amdgcn_global_load_lds)
#define HAVE_GLDS 1
__device__ __forceinline__ void glds16(const u16* g, u16* l) {
  __builtin_amdgcn_global_load_lds((const __attribute__((address_space(1))) void*)g,
                                   (__attribute__((address_space(3))) void*)l, 16, 0, 0);
}
#else
#define HAVE_GLDS 0
#endif

// stage 1KB per wave: per-lane global source gperlane (16B each), wave-uniform
// LDS dest lwave (HW adds lane*16B for glds; fallback does it manually).
__device__ __forceinline__ void stage1k(const u16* gperlane, u16* lwave, int lane) {
#if HAVE_GLDS
  (void)lane;
  glds16(gperlane, lwave);
#else
  *(uint4*)(lwave + lane * 8) = *(const uint4*)gperlane;
#endif
}

// XOR-swizzled LDS addressing for [64][64] u16 tiles (128B rows).
// byte ^= ((row&7)<<4). Measured: kills the stride-128B same-bank pattern
// (SQ_LDS_BANK_CONFLICT 5.9M -> 1.08M). The K/V tiles now arrive in global
// memory ALREADY swizzled (GEMM epilogue applies the XOR), so staging is a
// pure linear async copy and only the reads use swzp.
__device__ __forceinline__ u16* swzp(u16* base, int row, int bc) {
  return (u16*)((char*)base + row * 128 + (bc ^ ((row & 7) << 4)));
}

// ---------------- prep kernels ----------------

__global__ void k_convert_x(const float* __restrict__ in, u16* __restrict__ out, int n4) {
  int i = blockIdx.x * blockDim.x + threadIdx.x;
  if (i < n4) {
    float4 v = ((const float4*)in)[i];
    ushort4 o;
    o.x = f2bf(v.x); o.y = f2bf(v.y); o.z = f2bf(v.z); o.w = f2bf(v.w);
    ((ushort4*)out)[i] = o;
  }
}

__global__ void k_transpose_bf(const float* __restrict__ in, u16* __restrict__ out, int R, int C) {
  __shared__ float t[32][33];
  int c0 = blockIdx.x * 32, r0 = blockIdx.y * 32;
  int tx = threadIdx.x, ty = threadIdx.y;
#pragma unroll
  for (int k = 0; k < 4; k++) t[ty + 8 * k][tx] = in[(size_t)(r0 + ty + 8 * k) * C + c0 + tx];
  __syncthreads();
#pragma unroll
  for (int k = 0; k < 4; k++) out[(size_t)(c0 + ty + 8 * k) * R + r0 + tx] = f2bf(t[tx][ty + 8 * k]);
}

__global__ void k_tables(const float* __restrict__ cP, const float* __restrict__ lP,
                         float* __restrict__ ig2, float* __restrict__ rl) {
  int t = blockIdx.x * blockDim.x + threadIdx.x;
  float c = fabsf(cP[0]);
  if (t < 2048) {
    float lm = lP[0];
    float thr = fabsf(lm * 512.0f);
    float pn = fmaxf((float)t, thr);
    float den = logf(c * pn + 1.0f) + 1e-6f;
    ig2[t] = LN2 / den;
  }
  if (t < 2112) {
    int d = t - 63;
    if (d < 0) d = 0;
    rl[t] = log2f(c * (float)d + 1.0f);
  }
}

__global__ void k_segments(const float* __restrict__ w1, const float* __restrict__ b1,
                           const float* __restrict__ w2, const float* __restrict__ b2,
                           float* __restrict__ segX, float* __restrict__ segA,
                           float* __restrict__ segB, int* __restrict__ segU) {
  __shared__ float xs[32];
  __shared__ float srt[32];
  __shared__ float uniq[32];
  __shared__ int uCnt;
  int t = threadIdx.x;
  if (t < 32) {
    float w = w1[t], b = b1[t];
    xs[t] = (w != 0.0f) ? (-b / w) : INFF;
  }
  __syncthreads();
  if (t < 32) {
    float x = xs[t];
    int r = 0;
    for (int v = 0; v < 32; v++) {
      float xv = xs[v];
      if (xv < x || (xv == x && v < t)) r++;
    }
    srt[r] = x;
  }
  __syncthreads();
  if (t == 0) {
    int u = 0;
    for (int i = 0; i < 32; i++) {
      float v = srt[i];
      if (v < 3.0e38f && (u == 0 || v != uniq[u - 1])) uniq[u++] = v;
    }
    uCnt = u;
    segU[0] = u;
  }
  __syncthreads();
  int u = uCnt;
  if (t < u) segX[t] = uniq[t];
  for (int idx = t; idx < (u + 1) * 16; idx += blockDim.x) {
    int j = idx >> 4, h = idx & 15;
    float p;
    if (u == 0) p = 0.0f;
    else if (j == 0) p = uniq[0] - 1.0f;
    else if (j == u) p = uniq[u - 1] + 1.0f;
    else p = 0.5f * (uniq[j - 1] + uniq[j]);
    float A = b2[h], B = 0.0f;
    for (int w = 0; w < 32; w++) {
      float w1w = w1[w], b1w = b1[w], w2wh = w2[w * 16 + h];
      if (w1w != 0.0f) {
        if (fmaf(w1w, p, b1w) > 0.0f) { B += w1w * w2wh; A += b1w * w2wh; }
      } else if (b1w > 0.0f) {
        A += b1w * w2wh;
      }
    }
    segA[j * 16 + h] = A;
    segB[j * 16 + h] = B;
  }
}

// ---------------- GEMM:  C(MxN) = A(MxK) @ BT(NxK)^T ----------------
// MODE 0 (QKV): Q -> [bh][t][d] linear; K -> [bh][t][d] with per-row byte
// swizzle ^((t&7)<<4); V -> TRANSPOSED [bh][d][t] with per-row byte swizzle
// ^((d&7)<<4). The swizzled layouts make k_attn's LDS staging a pure linear
// async copy (global_load_lds) with conflict-free ds_read_b128 on the read.
template <int MODE, int BN>
__launch_bounds__(256, 3)
__global__ void k_gemm(const u16* __restrict__ A, const u16* __restrict__ BT,
                       const float* __restrict__ bias, float* __restrict__ outF,
                       u16* __restrict__ outQ, u16* __restrict__ outK, u16* __restrict__ outV,
                       int M, int N, int K) {
  constexpr int NT = BN / 32;
  constexpr int NCH = BN / 32;
  __shared__ u16 As[128 * 64];
  __shared__ u16 Bs[BN * 64];
  const int tid = threadIdx.x;
  const int lane = tid & 63, wave = tid >> 6;
  const int li = lane & 15, quad = lane >> 4;
  const int wrow = (wave >> 1) * 64, wcol = (wave & 1) * (BN / 2);
  const int rb = blockIdx.y * 128, cb = blockIdx.x * BN;

  f32x4 acc[4][NT];
#pragma unroll
  for (int i = 0; i < 4; i++)
#pragma unroll
    for (int j = 0; j < NT; j++) acc[i][j] = (f32x4){0.f, 0.f, 0.f, 0.f};

#if HAVE_GLDS
  const u16* gA = A + (size_t)(rb + (tid >> 3)) * K + (tid & 7) * 8;
  const u16* gB = BT + (size_t)(cb + (tid >> 3)) * K + (tid & 7) * 8;
  u16* lA = As + wave * 512;
  u16* lB = Bs + wave * 512;

  for (int k0 = 0; k0 < K; k0 += 64) {
    __syncthreads();
#pragma unroll
    for (int ch = 0; ch < 4; ch++) glds16(gA + (size_t)ch * 32 * K + k0, lA + ch * 2048);
#pragma unroll
    for (int ch = 0; ch < NCH; ch++) glds16(gB + (size_t)ch * 32 * K + k0, lB + ch * 2048);
    __syncthreads();
#pragma unroll
    for (int c = 0; c < 2; c++) {
      bf16x8 af[4], bfr[NT];
#pragma unroll
      for (int mt = 0; mt < 4; mt++)
        af[mt] = *(const bf16x8*)(&As[(wrow + mt * 16 + li) * 64 + c * 32 + quad * 8]);
#pragma unroll
      for (int nt = 0; nt < NT; nt++)
        bfr[nt] = *(const bf16x8*)(&Bs[(wcol + nt * 16 + li) * 64 + c * 32 + quad * 8]);
#pragma unroll
      for (int mt = 0; mt < 4; mt++)
#pragma unroll
        for (int nt = 0; nt < NT; nt++)
          acc[mt][nt] = __builtin_amdgcn_mfma_f32_16x16x32_bf16(af[mt], bfr[nt], acc[mt][nt], 0, 0, 0);
    }
  }
#else
  for (int k0 = 0; k0 < K; k0 += 64) {
    __syncthreads();
    for (int idx = tid * 8; idx < 128 * 64; idx += 256 * 8) {
      int rr = idx >> 6, cc = idx & 63;
      *(uint4*)(&As[idx]) = *(const uint4*)(A + (size_t)(rb + rr) * K + k0 + cc);
    }
    for (int idx = tid * 8; idx < BN * 64; idx += 256 * 8) {
      int rr = idx >> 6, cc = idx & 63;
      *(uint4*)(&Bs[idx]) = *(const uint4*)(BT + (size_t)(cb + rr) * K + k0 + cc);
    }
    __syncthreads();
#pragma unroll
    for (int c = 0; c < 2; c++) {
      bf16x8 af[4], bfr[NT];
#pragma unroll
      for (int mt = 0; mt < 4; mt++)
        af[mt] = *(const bf16x8*)(&As[(wrow + mt * 16 + li) * 64 + c * 32 + quad * 8]);
#pragma unroll
      for (int nt = 0; nt < NT; nt++)
        bfr[nt] = *(const bf16x8*)(&Bs[(wcol + nt * 16 + li) * 64 + c * 32 + quad * 8]);
#pragma unroll
      for (int mt = 0; mt < 4; mt++)
#pragma unroll
        for (int nt = 0; nt < NT; nt++)
          acc[mt][nt] = __builtin_amdgcn_mfma_f32_16x16x32_bf16(af[mt], bfr[nt], acc[mt][nt], 0, 0, 0);
    }
  }
#endif

#pragma unroll
  for (int mt = 0; mt < 4; mt++)
#pragma unroll
    for (int nt = 0; nt < NT; nt++) {
      const int col = cb + wcol + nt * 16 + li;
      const int row0 = rb + wrow + mt * 16 + quad * 4;
      float v[4];
#pragma unroll
      for (int r = 0; r < 4; r++) v[r] = acc[mt][nt][r] + bias[col];
      if (MODE == 0) {
        const int bb = row0 >> 11, tt0 = row0 & 2047;
        const int sel = col >> 10, w = col & 1023, hh = w >> 6, dd = w & 63;
        if (sel == 0) {
          u16* dst = outQ + ((size_t)((bb * 16 + hh) * 2048 + tt0)) * 64 + dd;
#pragma unroll
          for (int r = 0; r < 4; r++) dst[(size_t)r * 64] = f2bf(v[r]);
        } else if (sel == 1) {
          // K: row-swizzled [bh][t][d]
          u16* base = outK + ((size_t)((bb * 16 + hh) * 2048 + tt0)) * 64;
#pragma unroll
          for (int r = 0; r < 4; r++) {
            int tt = tt0 + r;
            base[(size_t)r * 64 + (dd ^ (((tt & 7)) << 3))] = f2bf(v[r]);
          }
        } else {
          // V: transposed+swizzled [bh][d][t], 4 consecutive t -> one 8B store
          u16* vrow = outV + ((size_t)((bb * 16 + hh) * 64 + dd)) * 2048;
          uint2 pk;
          pk.x = pack2bf_rne(v[0], v[1]);
          pk.y = pack2bf_rne(v[2], v[3]);
          *(uint2*)(vrow + (tt0 ^ ((dd & 7) << 3))) = pk;
        }
      } else {
#pragma unroll
        for (int r = 0; r < 4; r++) outF[(size_t)(row0 + r) * N + col] = v[r];
      }
    }
}

// ---------------- flash attention, S^T formulation ----------------
// Rounds 0-3 finding: per-iteration VALU work (~1200 cyc/wave) is the limit;
// occupancy is pinned ~20% regardless of grid schedule. This version cuts the
// per-iteration work:
//  - K/V staged via async global_load_lds from PRE-SWIZZLED global layouts
//    (V already transposed by GEMM) -> the 8-step V repack, K LDS writes and
//    the 4xuint4 register-prefetch machinery are gone.
//  - Double-buffered K/V tiles, ONE __syncthreads per iteration (its implicit
//    vmcnt(0) drain is the read-after-write wait; stage(nxt) issued after the
//    barrier overlaps the whole compute section).
//  - Bias fast path: when u<=1, x0r<=0, A0e==A1e (true for b1=0 data) the
//    segment select is row-uniform and the additive const cancels in softmax:
//    z = fma(rlv, B1g, sacc*SCL), 2 ops/element instead of 5.
// __launch_bounds__(256,3): (256,4) forces VGPR<=64 -> spill (round 1).
__launch_bounds__(256, 3)
__global__ void k_attn(const u16* __restrict__ Q, const u16* __restrict__ K,
                       const u16* __restrict__ Vt, u16* __restrict__ Y,
                       const float* __restrict__ ig2, const float* __restrict__ RL,
                       const float* __restrict__ segX, const float* __restrict__ segA,
                       const float* __restrict__ segB, const int* __restrict__ segU) {
  __shared__ u16 KsB[2 * 64 * 64];   // double-buffered, swizzled content
  __shared__ u16 VtsB[2 * 64 * 64];  // double-buffered, transposed+swizzled
  __shared__ u16 Ps[64 * 64];        // Ps[q][s] wave-private rows
  __shared__ float rls[2112];
  __shared__ float sXl[32];
  __shared__ float sAl[33];
  __shared__ float sBl[33];

  const int xi = blockIdx.x, h = blockIdx.y, b = blockIdx.z;
  const int q0b = xi >> 1;
  const int flip = (xi & 1) ^ ((h >> 3) & 1);
  const int qt = flip ? (31 - q0b) : q0b;

  const int tid = threadIdx.x, lane = tid & 63, wave = tid >> 6;
  const int li = lane & 15, quad = lane >> 4;
  const int bh = b * 16 + h;
  const u16* Qg = Q + (size_t)bh * 2048 * 64;
  const u16* Kg = K + (size_t)bh * 2048 * 64;
  const u16* Vg = Vt + (size_t)bh * 64 * 2048;

  for (int i = tid; i < 2112; i += 256) rls[i] = RL[i];

  const int u = segU[0];
  float x0 = INFF, A0, B0, A1, B1;
  A0 = segA[h]; B0 = segB[h]; A1 = A0; B1 = B0;
  if (u == 1) { x0 = segX[0]; A1 = segA[16 + h]; B1 = segB[16 + h]; }
  if (u > 1) {
    if (tid < u) sXl[tid] = segX[tid];
    if (tid < u + 1) { sAl[tid] = segA[tid * 16 + h]; sBl[tid] = segB[tid * 16 + h]; }
  }
  const float A0e = A0 * LOG2E, A1e = A1 * LOG2E;
  const float SCL = 0.125f * LOG2E;

  const int t = qt * 64 + wave * 16 + li;  // this lane's q-row
  bf16x8 qf[2];
#pragma unroll
  for (int c = 0; c < 2; c++)
    qf[c] = *(const bf16x8*)(Qg + (size_t)t * 64 + c * 32 + quad * 8);

  const float gI = ig2[t];
  const float x0r = x0 / gI;
  const float B0g = B0 * gI * LOG2E, B1g = B1 * gI * LOG2E;
  // fast path: select is row-uniform (all rlv>=0>=x0r take hi branch; at
  // rlv==0 both give the same A) and the additive A cancels in softmax.
  const bool uniB = (u <= 1) && (x0r <= 0.0f) && (A0e == A1e);
  float mrow = -INFF, lrow = 0.0f;
  f32x4 oacc[4];
#pragma unroll
  for (int nt = 0; nt < 4; nt++) oacc[nt] = (f32x4){0.f, 0.f, 0.f, 0.f};

  // per-lane staging bases (16B per lane, 1KB per wave per call)
  const u16* kgB = Kg + (size_t)(wave * 16 + (lane >> 3)) * 64 + (lane & 7) * 8;
  const u16* vgB = Vg + (size_t)(wave * 16 + (lane >> 3)) * 2048 + (lane & 7) * 8;

  auto stage = [&](int buf, int kt2) {
    u16* kd = KsB + buf * 4096 + wave * 1024;
    const u16* kg = kgB + (size_t)kt2 * 4096;
    stage1k(kg, kd, lane);
    stage1k(kg + 8 * 64, kd + 512, lane);
    u16* vd = VtsB + buf * 4096 + wave * 1024;
    const u16* vg = vgB + kt2 * 64;
    stage1k(vg, vd, lane);
    stage1k(vg + 8 * 2048, vd + 512, lane);
  };

  stage(0, 0);
  int cur = 0;

  for (int kt = 0; kt <= qt; kt++) {
    const int kb = kt * 64;
    // implicit vmcnt(0)+lgkmcnt(0) drain: cur tile's async loads landed in
    // every wave; all waves done reading the buffer stage() will overwrite.
    __syncthreads();
    if (kt < qt) stage(cur ^ 1, kt + 1);  // overlaps the whole compute below

    u16* KsT = KsB + cur * 4096;
    u16* VtT = VtsB + cur * 4096;

    // S^T = K Q^T : sacc[nt] row s = nt*16+quad*4+r, col q = li
    f32x4 sacc[4];
#pragma unroll
    for (int nt = 0; nt < 4; nt++) sacc[nt] = (f32x4){0.f, 0.f, 0.f, 0.f};
#pragma unroll
    for (int c = 0; c < 2; c++)
#pragma unroll
      for (int nt = 0; nt < 4; nt++) {
        bf16x8 kf = *(const bf16x8*)swzp(KsT, nt * 16 + li, c * 64 + quad * 16);
        sacc[nt] = __builtin_amdgcn_mfma_f32_16x16x32_bf16(kf, qf[c], sacc[nt], 0, 0, 0);
      }

    // bias via rl table (LDS)
    const int Cbase = t - kb - quad * 4 + 63;  // in [51, 2110]
    const float* rp = &rls[Cbase - 51];
    const int lim = Cbase - 63;
    if (uniB) {
#pragma unroll
      for (int nt = 0; nt < 4; nt++)
#pragma unroll
        for (int r = 0; r < 4; r++) {
          float z = fmaf(rp[51 - nt * 16 - r], B1g, sacc[nt][r] * SCL);
          if (kt == qt) z = (nt * 16 + r > lim) ? -INFF : z;
          sacc[nt][r] = z;
        }
    } else if (u <= 1) {
#pragma unroll
      for (int nt = 0; nt < 4; nt++)
#pragma unroll
        for (int r = 0; r < 4; r++) {
          float rlv = rp[51 - nt * 16 - r];
          bool hi = rlv > x0r;
          float z = fmaf(rlv, hi ? B1g : B0g, hi ? A1e : A0e);
          z = fmaf(sacc[nt][r], SCL, z);
          if (kt == qt) z = (nt * 16 + r > lim) ? -INFF : z;
          sacc[nt][r] = z;
        }
    } else {
#pragma unroll
      for (int nt = 0; nt < 4; nt++)
#pragma unroll
        for (int r = 0; r < 4; r++) {
          float nd = rp[51 - nt * 16 - r] * gI;
          int j = 0;
          for (int i = 0; i < u; i++) j += (nd > sXl[i]) ? 1 : 0;
          float z = (fmaf(nd, sBl[j], sAl[j]) + sacc[nt][r] * 0.125f) * LOG2E;
          if (kt == qt) z = (nt * 16 + r > lim) ? -INFF : z;
          sacc[nt][r] = z;
        }
    }

    // per-lane online softmax (row q = li) — tree-shaped max and sum
    f32x4 mm = sacc[0];
#pragma unroll
    for (int nt = 1; nt < 4; nt++)
#pragma unroll
      for (int r = 0; r < 4; r++) mm[r] = fmaxf(mm[r], sacc[nt][r]);
    float vm = fmaxf(fmaxf(mm[0], mm[1]), fmaxf(mm[2], mm[3]));
    vm = fmaxf(vm, __shfl_xor(vm, 16, 64));
    vm = fmaxf(vm, __shfl_xor(vm, 32, 64));
    float mnew = fmaxf(mrow, vm);
    bool grew = mnew > mrow;
    float alpha = __builtin_amdgcn_exp2f(mrow - mnew);
    mrow = mnew;
#pragma unroll
    for (int nt = 0; nt < 4; nt++)
#pragma unroll
      for (int r = 0; r < 4; r++)
        sacc[nt][r] = __builtin_amdgcn_exp2f(sacc[nt][r] - mnew);
    f32x4 sv = (sacc[0] + sacc[1]) + (sacc[2] + sacc[3]);
    float s = (sv[0] + sv[1]) + (sv[2] + sv[3]);
    s += __shfl_xor(s, 16, 64);
    s += __shfl_xor(s, 32, 64);
    lrow = lrow * alpha + s;
    if (__any(grew)) {  // skip the 16-mul rescale when no lane's max moved
#pragma unroll
      for (int nt = 0; nt < 4; nt++)
#pragma unroll
        for (int r = 0; r < 4; r++) oacc[nt][r] *= alpha;
    }

    // P^T -> Ps[q][s]; wave-private rows, b64 writes (no barrier needed)
    const int prow = wave * 16 + li;
#pragma unroll
    for (int nt = 0; nt < 4; nt++) {
      uint2 pk;
      pk.x = pack2bf(sacc[nt][0], sacc[nt][1]);
      pk.y = pack2bf(sacc[nt][2], sacc[nt][3]);
      *(uint2*)swzp(Ps, prow, 32 * nt + 8 * quad) = pk;
    }

    // O^T += V^T P^T
#pragma unroll
    for (int c = 0; c < 2; c++) {
      bf16x8 pf = *(const bf16x8*)swzp(Ps, prow, c * 64 + quad * 16);
#pragma unroll
      for (int nt = 0; nt < 4; nt++) {
        bf16x8 vf = *(const bf16x8*)swzp(VtT, nt * 16 + li, c * 64 + quad * 16);
        oacc[nt] = __builtin_amdgcn_mfma_f32_16x16x32_bf16(vf, pf, oacc[nt], 0, 0, 0);
      }
    }
    cur ^= 1;
  }

  // epilogue: O^T element (d = nt*16+quad*4+r, q = li) -> Y[b][t][h*64+d]
  float inv = 1.0f / lrow;
  u16* dst = Y + (size_t)(b * 2048 + t) * 1024 + h * 64 + quad * 4;
#pragma unroll
  for (int nt = 0; nt < 4; nt++) {
    uint2 pk;
    pk.x = pack2bf(oacc[nt][0] * inv, oacc[nt][1] * inv);
    pk.y = pack2bf(oacc[nt][2] * inv, oacc[nt][3] * inv);
    *(uint2*)(dst + nt * 16) = pk;
  }
}

// ---------------- launcher ----------------
extern "C" void kernel_launch(void* const* d_in, const int* in_sizes, int n_in,
                              void* d_out, int out_size, void* d_ws, size_t ws_size,
                              hipStream_t stream) {
  (void)in_sizes; (void)n_in; (void)out_size; (void)ws_size;
  const float* x = (const float*)d_in[0];
  const float* Wqkv = (const float*)d_in[1];
  const float* bqkv = (const float*)d_in[2];
  const float* Wproj = (const float*)d_in[3];
  const float* bproj = (const float*)d_in[4];
  const float* w1 = (const float*)d_in[5];
  const float* b1 = (const float*)d_in[6];
  const float* w2 = (const float*)d_in[7];
  const float* b2 = (const float*)d_in[8];
  const float* cP = (const float*)d_in[9];
  const float* lP = (const float*)d_in[10];

  char* ws = (char*)d_ws;
  u16* Xbf = (u16*)(ws);                          // 8 MB
  u16* WqkvT = (u16*)(ws + (size_t)(8 << 20));    // 6 MB
  u16* WprojT = (u16*)(ws + (size_t)(14 << 20));  // 2 MB
  u16* Qb = (u16*)(ws + (size_t)(16 << 20));      // 8 MB  [bh][t][d]
  u16* Kb = (u16*)(ws + (size_t)(24 << 20));      // 8 MB  [bh][t][d] swizzled
  u16* Vb = (u16*)(ws + (size_t)(32 << 20));      // 8 MB  [bh][d][t] swizzled
  u16* Yb = (u16*)(ws + (size_t)(40 << 20));      // 8 MB
  float* IG = (float*)(ws + (size_t)(48 << 20));  // tables
  float* RL = IG + 2048;
  float* SEGX = RL + 2112;
  float* SEGA = SEGX + 32;
  float* SEGB = SEGA + 33 * 16;
  int* SEGU = (int*)(SEGB + 33 * 16);

  k_convert_x<<<4096, 256, 0, stream>>>(x, Xbf, 1048576);
  k_transpose_bf<<<dim3(96, 32), dim3(32, 8), 0, stream>>>(Wqkv, WqkvT, 1024, 3072);
  k_transpose_bf<<<dim3(32, 32), dim3(32, 8), 0, stream>>>(Wproj, WprojT, 1024, 1024);
  k_tables<<<9, 256, 0, stream>>>(cP, lP, IG, RL);
  k_segments<<<1, 64, 0, stream>>>(w1, b1, w2, b2, SEGX, SEGA, SEGB, SEGU);

  k_gemm<0, 128><<<dim3(24, 32), 256, 0, stream>>>(Xbf, WqkvT, bqkv, nullptr, Qb, Kb, Vb,
                                                   4096, 3072, 1024);
  k_attn<<<dim3(32, 16, 2), 256, 0, stream>>>(Qb, Kb, Vb, Yb, IG, RL, SEGX, SEGA, SEGB, SEGU);
  k_gemm<1, 64><<<dim3(16, 32), 256, 0, stream>>>(Yb, WprojT, bproj, (float*)d_out, nullptr,
                                                  nullptr, nullptr, 4096, 1024, 1024);
}